// Round 1
// baseline (806.482 us; speedup 1.0000x reference)
//
#include <hip/hip_runtime.h>
#include <cstddef>

constexpr int S = 64, A = 16, MSG = 32, C = 4, CH = 73;
// ws layout (floats): W1T [80][64] @ 0, WaT [73][32] @ 5120, W3T [64][32] @ 7456
constexpr int W1T_OFF = 0, WAT_OFF = 5120, W3T_OFF = 7456;

__global__ void prep_transpose_kernel(const float* __restrict__ W1,
                                      const float* __restrict__ Wa,
                                      const float* __restrict__ W3,
                                      float* __restrict__ ws) {
  int t = blockIdx.x * blockDim.x + threadIdx.x;
  if (t < 64 * 80) { int j = t / 80, k = t % 80; ws[W1T_OFF + k * 64 + j] = W1[t]; }
  if (t < 32 * 73) { int j = t / 73, k = t % 73; ws[WAT_OFF + k * 32 + j] = Wa[t]; }
  if (t < 32 * 64) { int j = t / 64, k = t % 64; ws[W3T_OFF + k * 32 + j] = W3[t]; }
}

__device__ __forceinline__ float fast_tanh(float v) {
  v = fminf(15.f, fmaxf(-15.f, v));
  float t = __expf(2.f * v);
  return (t - 1.f) * __builtin_amdgcn_rcpf(t + 1.f);
}

__launch_bounds__(256)
__global__ void critic_fused_kernel(
    const float* __restrict__ x, const float* __restrict__ u,
    const float* __restrict__ cs, const float* __restrict__ m,
    const float* __restrict__ b1, const float* __restrict__ W2,
    const float* __restrict__ b2, const float* __restrict__ b3,
    const float* __restrict__ ba, const float* __restrict__ wsT,
    float* __restrict__ out, int n) {
  const int b = blockIdx.x * blockDim.x + threadIdx.x;
  if (b >= n) return;
  const float* __restrict__ W1T = wsT + W1T_OFF;  // [80][64]
  const float* __restrict__ WaT = wsT + WAT_OFF;  // [73][32]
  const float* __restrict__ W3T = wsT + W3T_OFF;  // [64][32]

  // ---------------- Phase A: attention over children -> magg[32] -------------
  float num[MSG], den[MSG];
#pragma unroll
  for (int j = 0; j < MSG; ++j) { num[j] = 0.f; den[j] = 0.f; }

  for (int c = 0; c < C; ++c) {
    float z[MSG];
#pragma unroll
    for (int j = 0; j < MSG; ++j) z[j] = ba[j];  // uniform -> s_load

    const float* __restrict__ csrow = cs + ((size_t)b * C + c) * CH;
    int k = 0;
    for (; k + 4 <= CH; k += 4) {  // dynamic loop, 18 iters
      float v0 = csrow[k + 0];
      float v1 = csrow[k + 1];
      float v2 = csrow[k + 2];
      float v3 = csrow[k + 3];
      const float* __restrict__ w0 = WaT + (k + 0) * MSG;
      const float* __restrict__ w1 = WaT + (k + 1) * MSG;
      const float* __restrict__ w2 = WaT + (k + 2) * MSG;
      const float* __restrict__ w3 = WaT + (k + 3) * MSG;
#pragma unroll
      for (int j = 0; j < MSG; ++j) {
        z[j] = fmaf(v0, w0[j], z[j]);
        z[j] = fmaf(v1, w1[j], z[j]);
        z[j] = fmaf(v2, w2[j], z[j]);
        z[j] = fmaf(v3, w3[j], z[j]);
      }
    }
    {  // remainder k = 72
      float v0 = csrow[72];
      const float* __restrict__ w0 = WaT + 72 * MSG;
#pragma unroll
      for (int j = 0; j < MSG; ++j) z[j] = fmaf(v0, w0[j], z[j]);
    }

    const float* __restrict__ mrow = m + (size_t)b * (C * MSG) + c * MSG;
    const float4* __restrict__ m4 = reinterpret_cast<const float4*>(mrow);
#pragma unroll
    for (int j4 = 0; j4 < MSG / 4; ++j4) {
      float4 mv = m4[j4];
      float ma[4] = {mv.x, mv.y, mv.z, mv.w};
#pragma unroll
      for (int jj = 0; jj < 4; ++jj) {
        int j = j4 * 4 + jj;
        float e = __expf(z[j]);
        den[j] += e;
        num[j] = fmaf(ma[jj], e, num[j]);
      }
    }
  }

  float magg[MSG];
#pragma unroll
  for (int j = 0; j < MSG; ++j) magg[j] = num[j] * __builtin_amdgcn_rcpf(den[j]);

  // ---------------- Phase B: fc1 on cat(x,u) -> h1[64] -----------------------
  float h1[64];
#pragma unroll
  for (int j = 0; j < 64; ++j) h1[j] = b1[j];  // uniform -> s_load

  const float4* __restrict__ xrow = reinterpret_cast<const float4*>(x + (size_t)b * S);
  for (int k4 = 0; k4 < S / 4; ++k4) {  // dynamic, 16 iters
    float4 xv = xrow[k4];
    float xa[4] = {xv.x, xv.y, xv.z, xv.w};
#pragma unroll
    for (int kk = 0; kk < 4; ++kk) {
      const float* __restrict__ w = W1T + (k4 * 4 + kk) * 64;
#pragma unroll
      for (int j = 0; j < 64; ++j) h1[j] = fmaf(xa[kk], w[j], h1[j]);
    }
  }
  const float4* __restrict__ urow = reinterpret_cast<const float4*>(u + (size_t)b * A);
  for (int k4 = 0; k4 < A / 4; ++k4) {  // dynamic, 4 iters
    float4 uv = urow[k4];
    float ua[4] = {uv.x, uv.y, uv.z, uv.w};
#pragma unroll
    for (int kk = 0; kk < 4; ++kk) {
      const float* __restrict__ w = W1T + (S + k4 * 4 + kk) * 64;
#pragma unroll
      for (int j = 0; j < 64; ++j) h1[j] = fmaf(ua[kk], w[j], h1[j]);
    }
  }

  // ---------------- Phase C: L2-normalize h1, tanh both parts ----------------
  float s0 = 0.f, s1 = 0.f, s2 = 0.f, s3 = 0.f;
#pragma unroll
  for (int j = 0; j < 64; j += 4) {
    s0 = fmaf(h1[j + 0], h1[j + 0], s0);
    s1 = fmaf(h1[j + 1], h1[j + 1], s1);
    s2 = fmaf(h1[j + 2], h1[j + 2], s2);
    s3 = fmaf(h1[j + 3], h1[j + 3], s3);
  }
  float rn = __builtin_amdgcn_rsqf(fmaxf((s0 + s1) + (s2 + s3), 1e-24f));

  float xua[64];
#pragma unroll
  for (int j = 0; j < 64; ++j) xua[j] = fast_tanh(h1[j] * rn);
  float xub[MSG];
#pragma unroll
  for (int j = 0; j < MSG; ++j) xub[j] = fast_tanh(magg[j]);

  // ---------------- Phase D: fc2(tanh) chained into fc3 ----------------------
  float o[MSG];
#pragma unroll
  for (int j = 0; j < MSG; ++j) o[j] = b3[j];  // uniform -> s_load

  for (int jb = 0; jb < 64; ++jb) {  // dynamic, 64 iters
    const float* __restrict__ w2r = W2 + jb * 96;  // original layout, row jb
    float a0 = b2[jb], a1 = 0.f, a2 = 0.f, a3 = 0.f;
#pragma unroll
    for (int k = 0; k < 64; k += 4) {
      a0 = fmaf(xua[k + 0], w2r[k + 0], a0);
      a1 = fmaf(xua[k + 1], w2r[k + 1], a1);
      a2 = fmaf(xua[k + 2], w2r[k + 2], a2);
      a3 = fmaf(xua[k + 3], w2r[k + 3], a3);
    }
#pragma unroll
    for (int k = 0; k < MSG; k += 4) {
      a0 = fmaf(xub[k + 0], w2r[64 + k + 0], a0);
      a1 = fmaf(xub[k + 1], w2r[64 + k + 1], a1);
      a2 = fmaf(xub[k + 2], w2r[64 + k + 2], a2);
      a3 = fmaf(xub[k + 3], w2r[64 + k + 3], a3);
    }
    float h2 = fast_tanh((a0 + a1) + (a2 + a3));
    const float* __restrict__ w3r = W3T + jb * MSG;
#pragma unroll
    for (int j = 0; j < MSG; ++j) o[j] = fmaf(h2, w3r[j], o[j]);
  }

  // ---------------- Phase E: final L2 norm + store ---------------------------
  float t0 = 0.f, t1 = 0.f, t2 = 0.f, t3 = 0.f;
#pragma unroll
  for (int j = 0; j < MSG; j += 4) {
    t0 = fmaf(o[j + 0], o[j + 0], t0);
    t1 = fmaf(o[j + 1], o[j + 1], t1);
    t2 = fmaf(o[j + 2], o[j + 2], t2);
    t3 = fmaf(o[j + 3], o[j + 3], t3);
  }
  float rn2 = __builtin_amdgcn_rsqf(fmaxf((t0 + t1) + (t2 + t3), 1e-24f));

  float4* __restrict__ orow = reinterpret_cast<float4*>(out + (size_t)b * MSG);
#pragma unroll
  for (int j4 = 0; j4 < MSG / 4; ++j4) {
    float4 ov;
    ov.x = o[j4 * 4 + 0] * rn2;
    ov.y = o[j4 * 4 + 1] * rn2;
    ov.z = o[j4 * 4 + 2] * rn2;
    ov.w = o[j4 * 4 + 3] * rn2;
    orow[j4] = ov;
  }
}

extern "C" void kernel_launch(void* const* d_in, const int* in_sizes, int n_in,
                              void* d_out, int out_size, void* d_ws, size_t ws_size,
                              hipStream_t stream) {
  const float* x  = (const float*)d_in[0];
  const float* u  = (const float*)d_in[1];
  const float* cs = (const float*)d_in[2];
  const float* m  = (const float*)d_in[3];
  const float* W1 = (const float*)d_in[4];
  const float* b1 = (const float*)d_in[5];
  const float* W2 = (const float*)d_in[6];
  const float* b2 = (const float*)d_in[7];
  const float* W3 = (const float*)d_in[8];
  const float* b3 = (const float*)d_in[9];
  const float* Wa = (const float*)d_in[10];
  const float* ba = (const float*)d_in[11];
  float* out = (float*)d_out;
  float* ws  = (float*)d_ws;

  const int n = in_sizes[0] / S;  // batch rows

  // transpose W1 -> W1T[80][64], Wa -> WaT[73][32], W3 -> W3T[64][32] into ws
  hipLaunchKernelGGL(prep_transpose_kernel, dim3(20), dim3(256), 0, stream,
                     W1, Wa, W3, ws);

  const int blocks = (n + 255) / 256;
  hipLaunchKernelGGL(critic_fused_kernel, dim3(blocks), dim3(256), 0, stream,
                     x, u, cs, m, b1, W2, b2, b3, ba, ws, out, n);
}